// Round 1
// baseline (1616.744 us; speedup 1.0000x reference)
//
#include <hip/hip_runtime.h>
#include <math.h>

#define N_NODES 50000
#define E_EDGES 800000
#define T_TYPES 3
#define FIN 256
#define NHEAD 4
#define DDIM 64
#define NEG_SLOPE 0.2f

// ---------------- edge-type attention table: ee[t][h] ----------------
__global__ void k_ee(const float* __restrict__ edge_emb, const float* __restrict__ W_e,
                     const float* __restrict__ attn_e, float* __restrict__ ee) {
    int j = threadIdx.x;            // 0..255 = h*64 + fe
    int h = j >> 6;
    int fe = j & 63;
    float ae = attn_e[h * 64 + fe];
    for (int t = 0; t < T_TYPES; ++t) {
        float v = 0.f;
        #pragma unroll
        for (int k = 0; k < 64; ++k) v += edge_emb[t * 64 + k] * W_e[k * 256 + j];
        v *= ae;
        #pragma unroll
        for (int o = 32; o; o >>= 1) v += __shfl_xor(v, o, 64);
        if ((j & 63) == 0) ee[t * 4 + h] = v;
    }
}

// ---------------- feat = x @ W, plus el/er per node ----------------
// block = 256 threads, tile = 64 nodes x 256 cols, BK = 32
__global__ __launch_bounds__(256) void k_gemm(const float* __restrict__ x, const float* __restrict__ W,
                                              const float* __restrict__ attn_l, const float* __restrict__ attn_r,
                                              float* __restrict__ feat, float* __restrict__ el,
                                              float* __restrict__ er) {
    __shared__ float xs[64][36];     // [m][k] pad to 36 (16B aligned rows)
    __shared__ float wsl[32][256];   // [k][n]
    const int tid = threadIdx.x;
    const int tx = tid & 63;         // col group: cols tx*4 .. tx*4+3
    const int ty = tid >> 6;         // row group: rows ty*16 .. ty*16+15
    const int m0 = blockIdx.x * 64;

    float acc[16][4];
    #pragma unroll
    for (int i = 0; i < 16; ++i)
        #pragma unroll
        for (int j = 0; j < 4; ++j) acc[i][j] = 0.f;

    for (int k0 = 0; k0 < 256; k0 += 32) {
        __syncthreads();
        // load x tile 64x32 (row-clamped)
        {
            int r = tid >> 3, kk4 = (tid & 7) * 4;
            #pragma unroll
            for (int rr = 0; rr < 64; rr += 32) {
                int gm = m0 + r + rr;
                if (gm >= N_NODES) gm = N_NODES - 1;
                float4 v = *reinterpret_cast<const float4*>(&x[(size_t)gm * 256 + k0 + kk4]);
                *reinterpret_cast<float4*>(&xs[r + rr][kk4]) = v;
            }
        }
        // load W tile 32x256
        {
            int c4 = (tid & 63) * 4, kr0 = tid >> 6;
            #pragma unroll
            for (int kr = 0; kr < 32; kr += 4) {
                float4 v = *reinterpret_cast<const float4*>(&W[(size_t)(k0 + kr + kr0) * 256 + c4]);
                *reinterpret_cast<float4*>(&wsl[kr + kr0][c4]) = v;
            }
        }
        __syncthreads();
        #pragma unroll
        for (int k4 = 0; k4 < 32; k4 += 4) {
            float4 wv0 = *reinterpret_cast<const float4*>(&wsl[k4 + 0][tx * 4]);
            float4 wv1 = *reinterpret_cast<const float4*>(&wsl[k4 + 1][tx * 4]);
            float4 wv2 = *reinterpret_cast<const float4*>(&wsl[k4 + 2][tx * 4]);
            float4 wv3 = *reinterpret_cast<const float4*>(&wsl[k4 + 3][tx * 4]);
            #pragma unroll
            for (int i = 0; i < 16; ++i) {
                float4 xv = *reinterpret_cast<const float4*>(&xs[ty * 16 + i][k4]);
                acc[i][0] += xv.x * wv0.x + xv.y * wv1.x + xv.z * wv2.x + xv.w * wv3.x;
                acc[i][1] += xv.x * wv0.y + xv.y * wv1.y + xv.z * wv2.y + xv.w * wv3.y;
                acc[i][2] += xv.x * wv0.z + xv.y * wv1.z + xv.z * wv2.z + xv.w * wv3.z;
                acc[i][3] += xv.x * wv0.w + xv.y * wv1.w + xv.z * wv2.w + xv.w * wv3.w;
            }
        }
    }

    // epilogue: write feat, reduce el/er across the 16 lanes of each head
    float4 al = *reinterpret_cast<const float4*>(&attn_l[tx * 4]);
    float4 ar = *reinterpret_cast<const float4*>(&attn_r[tx * 4]);
    const int h = tx >> 4;
    #pragma unroll
    for (int i = 0; i < 16; ++i) {
        int m = m0 + ty * 16 + i;
        float4 v;
        v.x = acc[i][0]; v.y = acc[i][1]; v.z = acc[i][2]; v.w = acc[i][3];
        if (m < N_NODES)
            *reinterpret_cast<float4*>(&feat[(size_t)m * 256 + tx * 4]) = v;
        float pl = v.x * al.x + v.y * al.y + v.z * al.z + v.w * al.w;
        float pr = v.x * ar.x + v.y * ar.y + v.z * ar.z + v.w * ar.w;
        #pragma unroll
        for (int o = 1; o < 16; o <<= 1) {
            pl += __shfl_xor(pl, o, 64);
            pr += __shfl_xor(pr, o, 64);
        }
        if ((tx & 15) == 0 && m < N_NODES) {
            el[m * 4 + h] = pl;
            er[m * 4 + h] = pr;
        }
    }
}

// ---------------- CSR build ----------------
__global__ void k_hist(const int* __restrict__ edst, unsigned* __restrict__ deg) {
    int e = blockIdx.x * 256 + threadIdx.x;
    if (e < E_EDGES) atomicAdd(&deg[edst[e]], 1u);
}

__global__ void k_alloc(const unsigned* __restrict__ deg, unsigned* __restrict__ off,
                        unsigned* __restrict__ cursor, unsigned* __restrict__ counter) {
    int n = blockIdx.x * 256 + threadIdx.x;
    if (n < N_NODES) {
        unsigned o = atomicAdd(counter, deg[n]);
        off[n] = o;
        cursor[n] = o;
    }
}

__global__ void k_scatter(const int* __restrict__ esrc, const int* __restrict__ edst,
                          const int* __restrict__ etype, const float* __restrict__ el,
                          const float* __restrict__ er, const float* __restrict__ ee,
                          unsigned* __restrict__ cursor, unsigned* __restrict__ ssrc,
                          unsigned* __restrict__ seid, float* __restrict__ slogit) {
    int e = blockIdx.x * 256 + threadIdx.x;
    if (e >= E_EDGES) return;
    int s = esrc[e], d = edst[e], t = etype[e];
    unsigned pos = atomicAdd(&cursor[d], 1u);
    ssrc[pos] = (unsigned)s;
    seid[pos] = (unsigned)e;
    float4 l = *reinterpret_cast<const float4*>(&el[s * 4]);
    float4 r = *reinterpret_cast<const float4*>(&er[d * 4]);
    float4 q = *reinterpret_cast<const float4*>(&ee[t * 4]);
    float4 z;
    z.x = l.x + r.x + q.x;
    z.y = l.y + r.y + q.y;
    z.z = l.z + r.z + q.z;
    z.w = l.w + r.w + q.w;
    z.x = z.x > 0.f ? z.x : NEG_SLOPE * z.x;
    z.y = z.y > 0.f ? z.y : NEG_SLOPE * z.y;
    z.z = z.z > 0.f ? z.z : NEG_SLOPE * z.z;
    z.w = z.w > 0.f ? z.w : NEG_SLOPE * z.w;
    *reinterpret_cast<float4*>(&slogit[(size_t)pos * 4]) = z;
}

// ---------------- per-dst softmax + aggregation (one wave per node) ----------------
__global__ __launch_bounds__(256) void k_agg(const unsigned* __restrict__ off, const unsigned* __restrict__ deg,
                                             const unsigned* __restrict__ ssrc, const unsigned* __restrict__ seid,
                                             const float* __restrict__ slogit, const float* __restrict__ feat,
                                             float* __restrict__ out, float* __restrict__ a_out) {
    const int wave = threadIdx.x >> 6;
    const int lane = threadIdx.x & 63;
    const int n = blockIdx.x * 4 + wave;
    if (n >= N_NODES) return;
    const int h = lane >> 4;
    const int q = lane & 15;
    const unsigned start = off[n];
    const unsigned cnt = deg[n];

    // pass A: max
    float m = -1e30f;
    for (unsigned i = 0; i < cnt; ++i)
        m = fmaxf(m, slogit[(size_t)(start + i) * 4 + h]);

    // pass B: sum + weighted aggregate
    float s = 0.f;
    float4 acc = {0.f, 0.f, 0.f, 0.f};
    for (unsigned i = 0; i < cnt; ++i) {
        float lg = slogit[(size_t)(start + i) * 4 + h];
        float w = __expf(lg - m);
        s += w;
        unsigned src = ssrc[start + i];
        float4 f = *reinterpret_cast<const float4*>(&feat[(size_t)src * 256 + h * 64 + q * 4]);
        acc.x += w * f.x;
        acc.y += w * f.y;
        acc.z += w * f.z;
        acc.w += w * f.w;
    }
    float inv = (cnt > 0) ? 1.f / s : 0.f;
    float4 o;
    o.x = acc.x * inv; o.y = acc.y * inv; o.z = acc.z * inv; o.w = acc.w * inv;
    *reinterpret_cast<float4*>(&out[(size_t)n * 256 + h * 64 + q * 4]) = o;

    // pass C: normalized attention back to original edge order
    if (q == 0) {
        for (unsigned i = 0; i < cnt; ++i) {
            float lg = slogit[(size_t)(start + i) * 4 + h];
            float aa = __expf(lg - m) * inv;
            a_out[(size_t)seid[start + i] * 4 + h] = aa;
        }
    }
}

extern "C" void kernel_launch(void* const* d_in, const int* in_sizes, int n_in,
                              void* d_out, int out_size, void* d_ws, size_t ws_size,
                              hipStream_t stream) {
    const float* x        = (const float*)d_in[0];
    const int*   edge_src = (const int*)d_in[1];
    const int*   edge_dst = (const int*)d_in[2];
    const int*   edge_type= (const int*)d_in[3];
    const float* W        = (const float*)d_in[4];
    const float* edge_emb = (const float*)d_in[5];
    const float* W_e      = (const float*)d_in[6];
    const float* attn_l   = (const float*)d_in[7];
    const float* attn_r   = (const float*)d_in[8];
    const float* attn_e   = (const float*)d_in[9];

    float* out   = (float*)d_out;                              // N*H*D
    float* a_out = (float*)d_out + (size_t)N_NODES * 256;      // E*H

    // workspace layout (byte offsets)
    char* ws = (char*)d_ws;
    float*    feat    = (float*)(ws + 0);                         // 51,200,000 B
    float*    el      = (float*)(ws + 51200000);                  // 800,000 B
    float*    er      = (float*)(ws + 52000000);                  // 800,000 B
    float*    ee      = (float*)(ws + 52800000);                  // 64 B
    unsigned* deg     = (unsigned*)(ws + 52800064);               // 200,000 B
    unsigned* off     = (unsigned*)(ws + 53000064);               // 200,000 B
    unsigned* cursor  = (unsigned*)(ws + 53200064);               // 200,000 B
    unsigned* counter = (unsigned*)(ws + 53400064);               // 64 B
    unsigned* ssrc    = (unsigned*)(ws + 53400128);               // 3,200,000 B
    unsigned* seid    = (unsigned*)(ws + 56600128);               // 3,200,000 B
    float*    slogit  = (float*)(ws + 59800128);                  // 12,800,000 B
    // total: 72,600,128 B

    hipMemsetAsync(deg, 0, 200000, stream);
    hipMemsetAsync(counter, 0, 64, stream);

    k_ee<<<1, 256, 0, stream>>>(edge_emb, W_e, attn_e, ee);
    k_gemm<<<(N_NODES + 63) / 64, 256, 0, stream>>>(x, W, attn_l, attn_r, feat, el, er);
    k_hist<<<(E_EDGES + 255) / 256, 256, 0, stream>>>(edge_dst, deg);
    k_alloc<<<(N_NODES + 255) / 256, 256, 0, stream>>>(deg, off, cursor, counter);
    k_scatter<<<(E_EDGES + 255) / 256, 256, 0, stream>>>(edge_src, edge_dst, edge_type,
                                                         el, er, ee, cursor, ssrc, seid, slogit);
    k_agg<<<(N_NODES + 3) / 4, 256, 0, stream>>>(off, deg, ssrc, seid, slogit, feat, out, a_out);
}

// Round 2
// 279.253 us; speedup vs baseline: 5.7895x; 5.7895x over previous
//
#include <hip/hip_runtime.h>
#include <hip/hip_bf16.h>
#include <math.h>

#define N_NODES 50000
#define E_EDGES 800000
#define T_TYPES 3
#define NEG_SLOPE 0.2f

typedef __attribute__((ext_vector_type(8))) short short8;
typedef __attribute__((ext_vector_type(4))) float f32x4;

__device__ inline short f2bf(float f) {
    __hip_bfloat16 h = __float2bfloat16(f);
    union { __hip_bfloat16 b; short s; } u;
    u.b = h;
    return u.s;
}

// ---------------- W transpose + bf16 convert: Wt[n][k] = bf16(W[k][n]) ----------------
__global__ void k_wt(const float* __restrict__ W, short* __restrict__ Wt) {
    int n = blockIdx.x;
    int k = threadIdx.x;
    Wt[n * 256 + k] = f2bf(W[k * 256 + n]);
}

// ---------------- edge-type attention table: ee[t][h] ----------------
__global__ void k_ee(const float* __restrict__ edge_emb, const float* __restrict__ W_e,
                     const float* __restrict__ attn_e, float* __restrict__ ee) {
    int j = threadIdx.x;            // 0..255 = h*64 + fe
    int h = j >> 6;
    float ae = attn_e[j];           // attn_e[h*64+fe]
    for (int t = 0; t < T_TYPES; ++t) {
        float v = 0.f;
        #pragma unroll
        for (int k = 0; k < 64; ++k) v += edge_emb[t * 64 + k] * W_e[k * 256 + j];
        v *= ae;
        #pragma unroll
        for (int o = 32; o; o >>= 1) v += __shfl_xor(v, o, 64);
        if ((j & 63) == 0) ee[t * 4 + h] = v;
    }
}

// ---------------- feat = x @ W via bf16 MFMA, fused el/er ----------------
// block = 512 threads (8 waves, 2 row x 4 col), tile 128 x 256 (full N), BK = 32
__global__ __launch_bounds__(512) void k_gemm(const float* __restrict__ x, const short* __restrict__ Wt,
                                              const float* __restrict__ attn_l, const float* __restrict__ attn_r,
                                              float* __restrict__ feat, float* __restrict__ el,
                                              float* __restrict__ er) {
    __shared__ short a_lds[128 * 40];   // [m][k] rows padded to 40 shorts (80 B, 16B-aligned)
    const int tid = threadIdx.x;
    const int wid = tid >> 6;
    const int lane = tid & 63;
    const int wr = wid >> 2;            // 0..1 (row half)
    const int wc = wid & 3;             // 0..3 (col quarter == head)
    const int l15 = lane & 15;
    const int lq = lane >> 4;           // 0..3
    const int m0 = blockIdx.x * 128;

    f32x4 acc[4][4];
    #pragma unroll
    for (int mf = 0; mf < 4; ++mf)
        #pragma unroll
        for (int nf = 0; nf < 4; ++nf)
            acc[mf][nf] = (f32x4){0.f, 0.f, 0.f, 0.f};

    // staging assignment: thread t -> row t>>2, 8-col chunk (t&3)*8
    const int sr = tid >> 2;
    const int sc = (tid & 3) * 8;
    int gm = m0 + sr;
    if (gm >= N_NODES) gm = N_NODES - 1;
    const float* xrow = &x[(size_t)gm * 256];

    #pragma unroll
    for (int k0 = 0; k0 < 256; k0 += 32) {
        float4 v0 = *reinterpret_cast<const float4*>(&xrow[k0 + sc]);
        float4 v1 = *reinterpret_cast<const float4*>(&xrow[k0 + sc + 4]);
        short8 s;
        s[0] = f2bf(v0.x); s[1] = f2bf(v0.y); s[2] = f2bf(v0.z); s[3] = f2bf(v0.w);
        s[4] = f2bf(v1.x); s[5] = f2bf(v1.y); s[6] = f2bf(v1.z); s[7] = f2bf(v1.w);
        *reinterpret_cast<short8*>(&a_lds[sr * 40 + sc]) = s;
        __syncthreads();

        short8 av[4], bv[4];
        #pragma unroll
        for (int mf = 0; mf < 4; ++mf) {
            int row = wr * 64 + mf * 16 + l15;
            av[mf] = *reinterpret_cast<const short8*>(&a_lds[row * 40 + lq * 8]);
        }
        #pragma unroll
        for (int nf = 0; nf < 4; ++nf) {
            int n = wc * 64 + nf * 16 + l15;
            bv[nf] = *reinterpret_cast<const short8*>(&Wt[(size_t)n * 256 + k0 + lq * 8]);
        }
        #pragma unroll
        for (int mf = 0; mf < 4; ++mf)
            #pragma unroll
            for (int nf = 0; nf < 4; ++nf)
                acc[mf][nf] = __builtin_amdgcn_mfma_f32_16x16x32_bf16(av[mf], bv[nf], acc[mf][nf], 0, 0, 0);
        __syncthreads();
    }

    // epilogue: write feat + fused el/er (wave wc owns exactly head wc's 64 cols)
    float al[4], ar[4];
    #pragma unroll
    for (int nf = 0; nf < 4; ++nf) {
        al[nf] = attn_l[wc * 64 + nf * 16 + l15];
        ar[nf] = attn_r[wc * 64 + nf * 16 + l15];
    }
    #pragma unroll
    for (int mf = 0; mf < 4; ++mf) {
        #pragma unroll
        for (int i = 0; i < 4; ++i) {
            int m = m0 + wr * 64 + mf * 16 + lq * 4 + i;
            bool ok = m < N_NODES;
            float pl = 0.f, pr = 0.f;
            #pragma unroll
            for (int nf = 0; nf < 4; ++nf) {
                float v = acc[mf][nf][i];
                if (ok) feat[(size_t)m * 256 + wc * 64 + nf * 16 + l15] = v;
                pl += v * al[nf];
                pr += v * ar[nf];
            }
            #pragma unroll
            for (int o = 1; o < 16; o <<= 1) {
                pl += __shfl_xor(pl, o, 64);
                pr += __shfl_xor(pr, o, 64);
            }
            if (ok && l15 == 0) {
                el[m * 4 + wc] = pl;
                er[m * 4 + wc] = pr;
            }
        }
    }
}

// ---------------- CSR build ----------------
__global__ void k_hist(const int* __restrict__ edst, unsigned* __restrict__ deg) {
    int e = blockIdx.x * 256 + threadIdx.x;
    if (e < E_EDGES) atomicAdd(&deg[edst[e]], 1u);
}

__global__ void k_alloc(const unsigned* __restrict__ deg, unsigned* __restrict__ off,
                        unsigned* __restrict__ cursor, unsigned* __restrict__ counter) {
    int n = blockIdx.x * 256 + threadIdx.x;
    if (n < N_NODES) {
        unsigned o = atomicAdd(counter, deg[n]);
        off[n] = o;
        cursor[n] = o;
    }
}

__global__ void k_scatter(const int* __restrict__ esrc, const int* __restrict__ edst,
                          const int* __restrict__ etype, const float* __restrict__ el,
                          const float* __restrict__ er, const float* __restrict__ ee,
                          unsigned* __restrict__ cursor, unsigned* __restrict__ ssrc,
                          unsigned* __restrict__ seid, float* __restrict__ slogit) {
    int e = blockIdx.x * 256 + threadIdx.x;
    if (e >= E_EDGES) return;
    int s = esrc[e], d = edst[e], t = etype[e];
    unsigned pos = atomicAdd(&cursor[d], 1u);
    ssrc[pos] = (unsigned)s;
    seid[pos] = (unsigned)e;
    float4 l = *reinterpret_cast<const float4*>(&el[s * 4]);
    float4 r = *reinterpret_cast<const float4*>(&er[d * 4]);
    float4 q = *reinterpret_cast<const float4*>(&ee[t * 4]);
    float4 z;
    z.x = l.x + r.x + q.x;
    z.y = l.y + r.y + q.y;
    z.z = l.z + r.z + q.z;
    z.w = l.w + r.w + q.w;
    z.x = z.x > 0.f ? z.x : NEG_SLOPE * z.x;
    z.y = z.y > 0.f ? z.y : NEG_SLOPE * z.y;
    z.z = z.z > 0.f ? z.z : NEG_SLOPE * z.z;
    z.w = z.w > 0.f ? z.w : NEG_SLOPE * z.w;
    *reinterpret_cast<float4*>(&slogit[(size_t)pos * 4]) = z;
}

// ---------------- per-dst softmax + aggregation (one wave per node) ----------------
__global__ __launch_bounds__(256) void k_agg(const unsigned* __restrict__ off, const unsigned* __restrict__ deg,
                                             const unsigned* __restrict__ ssrc, const unsigned* __restrict__ seid,
                                             const float* __restrict__ slogit, const float* __restrict__ feat,
                                             float* __restrict__ out, float* __restrict__ a_out) {
    const int wave = threadIdx.x >> 6;
    const int lane = threadIdx.x & 63;
    const int n = blockIdx.x * 4 + wave;
    if (n >= N_NODES) return;
    const int h = lane >> 4;
    const int q = lane & 15;
    const unsigned start = off[n];
    const unsigned cnt = deg[n];

    // pass A: max (uniform across the 16 lanes of each head)
    float m = -1e30f;
    for (unsigned i = 0; i < cnt; ++i)
        m = fmaxf(m, slogit[(size_t)(start + i) * 4 + h]);

    // pass B: sum + weighted aggregate
    float s = 0.f;
    float4 acc = {0.f, 0.f, 0.f, 0.f};
    for (unsigned i = 0; i < cnt; ++i) {
        float lg = slogit[(size_t)(start + i) * 4 + h];
        float w = __expf(lg - m);
        s += w;
        unsigned src = ssrc[start + i];
        float4 f = *reinterpret_cast<const float4*>(&feat[(size_t)src * 256 + h * 64 + q * 4]);
        acc.x += w * f.x;
        acc.y += w * f.y;
        acc.z += w * f.z;
        acc.w += w * f.w;
    }
    float inv = (cnt > 0) ? 1.f / s : 0.f;
    float4 o;
    o.x = acc.x * inv; o.y = acc.y * inv; o.z = acc.z * inv; o.w = acc.w * inv;
    *reinterpret_cast<float4*>(&out[(size_t)n * 256 + h * 64 + q * 4]) = o;

    // pass C: normalized attention back to original edge order — all 64 lanes
    float m_h[4], inv_h[4];
    #pragma unroll
    for (int hh = 0; hh < 4; ++hh) {
        m_h[hh] = __shfl(m, hh * 16, 64);
        inv_h[hh] = __shfl(inv, hh * 16, 64);
    }
    const int hh = lane & 3;
    for (unsigned i = lane >> 2; i < cnt; i += 16) {
        float lg = slogit[(size_t)(start + i) * 4 + hh];
        a_out[(size_t)seid[start + i] * 4 + hh] = __expf(lg - m_h[hh]) * inv_h[hh];
    }
}

extern "C" void kernel_launch(void* const* d_in, const int* in_sizes, int n_in,
                              void* d_out, int out_size, void* d_ws, size_t ws_size,
                              hipStream_t stream) {
    const float* x        = (const float*)d_in[0];
    const int*   edge_src = (const int*)d_in[1];
    const int*   edge_dst = (const int*)d_in[2];
    const int*   edge_type= (const int*)d_in[3];
    const float* W        = (const float*)d_in[4];
    const float* edge_emb = (const float*)d_in[5];
    const float* W_e      = (const float*)d_in[6];
    const float* attn_l   = (const float*)d_in[7];
    const float* attn_r   = (const float*)d_in[8];
    const float* attn_e   = (const float*)d_in[9];

    float* out   = (float*)d_out;                              // N*H*D
    float* a_out = (float*)d_out + (size_t)N_NODES * 256;      // E*H

    // workspace layout (byte offsets)
    char* ws = (char*)d_ws;
    float*    feat    = (float*)(ws + 0);                         // 51,200,000 B
    float*    el      = (float*)(ws + 51200000);                  // 800,000 B
    float*    er      = (float*)(ws + 52000000);                  // 800,000 B
    float*    ee      = (float*)(ws + 52800000);                  // 64 B
    unsigned* deg     = (unsigned*)(ws + 52800064);               // 200,000 B
    unsigned* off     = (unsigned*)(ws + 53000064);               // 200,000 B
    unsigned* cursor  = (unsigned*)(ws + 53200064);               // 200,000 B
    unsigned* counter = (unsigned*)(ws + 53400064);               // 64 B
    unsigned* ssrc    = (unsigned*)(ws + 53400128);               // 3,200,000 B
    unsigned* seid    = (unsigned*)(ws + 56600128);               // 3,200,000 B
    float*    slogit  = (float*)(ws + 59800128);                  // 12,800,000 B
    // Wt (bf16 256x256, 131072 B) aliases the seid region: dead before k_scatter writes seid
    short*    Wt      = (short*)(ws + 56600128);

    hipMemsetAsync(deg, 0, 200000, stream);
    hipMemsetAsync(counter, 0, 64, stream);

    k_wt<<<256, 256, 0, stream>>>(W, Wt);
    k_ee<<<1, 256, 0, stream>>>(edge_emb, W_e, attn_e, ee);
    k_gemm<<<(N_NODES + 127) / 128, 512, 0, stream>>>(x, Wt, attn_l, attn_r, feat, el, er);
    k_hist<<<(E_EDGES + 255) / 256, 256, 0, stream>>>(edge_dst, deg);
    k_alloc<<<(N_NODES + 255) / 256, 256, 0, stream>>>(deg, off, cursor, counter);
    k_scatter<<<(E_EDGES + 255) / 256, 256, 0, stream>>>(edge_src, edge_dst, edge_type,
                                                         el, er, ee, cursor, ssrc, seid, slogit);
    k_agg<<<(N_NODES + 3) / 4, 256, 0, stream>>>(off, deg, ssrc, seid, slogit, feat, out, a_out);
}

// Round 3
// 228.969 us; speedup vs baseline: 7.0610x; 1.2196x over previous
//
#include <hip/hip_runtime.h>
#include <hip/hip_bf16.h>
#include <math.h>

#define N_NODES 50000
#define E_EDGES 800000
#define T_TYPES 3
#define NEG_SLOPE 0.2f

typedef __attribute__((ext_vector_type(8))) short short8;
typedef __attribute__((ext_vector_type(4))) float f32x4;

__device__ inline short f2bf(float f) {
    __hip_bfloat16 h = __float2bfloat16(f);
    union { __hip_bfloat16 b; short s; } u;
    u.b = h;
    return u.s;
}
__device__ inline float bf2f(short s) {
    union { unsigned u; float f; } v;
    v.u = ((unsigned)(unsigned short)s) << 16;
    return v.f;
}

// ---------------- W transpose + bf16 convert: Wt[n][k] = bf16(W[k][n]) ----------------
__global__ void k_wt(const float* __restrict__ W, short* __restrict__ Wt) {
    int n = blockIdx.x;
    int k = threadIdx.x;
    Wt[n * 256 + k] = f2bf(W[k * 256 + n]);
}

// ---------------- edge-type attention table: ee[t][h], one block per t ----------------
__global__ void k_ee(const float* __restrict__ edge_emb, const float* __restrict__ W_e,
                     const float* __restrict__ attn_e, float* __restrict__ ee) {
    int j = threadIdx.x;            // 0..255 = h*64 + fe
    int h = j >> 6;
    int t = blockIdx.x;
    float ae = attn_e[j];
    float v = 0.f;
    #pragma unroll
    for (int k = 0; k < 64; ++k) v += edge_emb[t * 64 + k] * W_e[k * 256 + j];
    v *= ae;
    #pragma unroll
    for (int o = 32; o; o >>= 1) v += __shfl_xor(v, o, 64);
    if ((j & 63) == 0) ee[t * 4 + h] = v;
}

// ---------------- feat(bf16) = x @ W via bf16 MFMA, fused el/er ----------------
// block = 512 threads (8 waves, 2 row x 4 col), tile 128 x 256 (full N), BK = 32
__global__ __launch_bounds__(512) void k_gemm(const float* __restrict__ x, const short* __restrict__ Wt,
                                              const float* __restrict__ attn_l, const float* __restrict__ attn_r,
                                              short* __restrict__ featb, float* __restrict__ el,
                                              float* __restrict__ er) {
    __shared__ short a_lds[128 * 40];   // [m][k] rows padded to 40 shorts
    const int tid = threadIdx.x;
    const int wid = tid >> 6;
    const int lane = tid & 63;
    const int wr = wid >> 2;            // 0..1 (row half)
    const int wc = wid & 3;             // 0..3 (col quarter == head)
    const int l15 = lane & 15;
    const int lq = lane >> 4;           // 0..3
    const int m0 = blockIdx.x * 128;

    f32x4 acc[4][4];
    #pragma unroll
    for (int mf = 0; mf < 4; ++mf)
        #pragma unroll
        for (int nf = 0; nf < 4; ++nf)
            acc[mf][nf] = (f32x4){0.f, 0.f, 0.f, 0.f};

    const int sr = tid >> 2;
    const int sc = (tid & 3) * 8;
    int gm = m0 + sr;
    if (gm >= N_NODES) gm = N_NODES - 1;
    const float* xrow = &x[(size_t)gm * 256];

    #pragma unroll
    for (int k0 = 0; k0 < 256; k0 += 32) {
        float4 v0 = *reinterpret_cast<const float4*>(&xrow[k0 + sc]);
        float4 v1 = *reinterpret_cast<const float4*>(&xrow[k0 + sc + 4]);
        short8 s;
        s[0] = f2bf(v0.x); s[1] = f2bf(v0.y); s[2] = f2bf(v0.z); s[3] = f2bf(v0.w);
        s[4] = f2bf(v1.x); s[5] = f2bf(v1.y); s[6] = f2bf(v1.z); s[7] = f2bf(v1.w);
        *reinterpret_cast<short8*>(&a_lds[sr * 40 + sc]) = s;
        __syncthreads();

        short8 av[4], bv[4];
        #pragma unroll
        for (int mf = 0; mf < 4; ++mf) {
            int row = wr * 64 + mf * 16 + l15;
            av[mf] = *reinterpret_cast<const short8*>(&a_lds[row * 40 + lq * 8]);
        }
        #pragma unroll
        for (int nf = 0; nf < 4; ++nf) {
            int n = wc * 64 + nf * 16 + l15;
            bv[nf] = *reinterpret_cast<const short8*>(&Wt[(size_t)n * 256 + k0 + lq * 8]);
        }
        #pragma unroll
        for (int mf = 0; mf < 4; ++mf)
            #pragma unroll
            for (int nf = 0; nf < 4; ++nf)
                acc[mf][nf] = __builtin_amdgcn_mfma_f32_16x16x32_bf16(av[mf], bv[nf], acc[mf][nf], 0, 0, 0);
        __syncthreads();
    }

    // epilogue: write bf16 feat + fused el/er (f32 accuracy for logits)
    float al[4], ar[4];
    #pragma unroll
    for (int nf = 0; nf < 4; ++nf) {
        al[nf] = attn_l[wc * 64 + nf * 16 + l15];
        ar[nf] = attn_r[wc * 64 + nf * 16 + l15];
    }
    #pragma unroll
    for (int mf = 0; mf < 4; ++mf) {
        #pragma unroll
        for (int i = 0; i < 4; ++i) {
            int m = m0 + wr * 64 + mf * 16 + lq * 4 + i;
            bool ok = m < N_NODES;
            float pl = 0.f, pr = 0.f;
            #pragma unroll
            for (int nf = 0; nf < 4; ++nf) {
                float v = acc[mf][nf][i];
                if (ok) featb[(size_t)m * 256 + wc * 64 + nf * 16 + l15] = f2bf(v);
                pl += v * al[nf];
                pr += v * ar[nf];
            }
            #pragma unroll
            for (int o = 1; o < 16; o <<= 1) {
                pl += __shfl_xor(pl, o, 64);
                pr += __shfl_xor(pr, o, 64);
            }
            if (ok && l15 == 0) {
                el[m * 4 + wc] = pl;
                er[m * 4 + wc] = pr;
            }
        }
    }
}

// ---------------- CSR build ----------------
__global__ void k_hist(const int* __restrict__ edst, unsigned* __restrict__ deg) {
    int e = blockIdx.x * 256 + threadIdx.x;
    if (e < E_EDGES) atomicAdd(&deg[edst[e]], 1u);
}

__global__ void k_alloc(const unsigned* __restrict__ deg, unsigned* __restrict__ off,
                        unsigned* __restrict__ cursor, unsigned* __restrict__ counter) {
    int n = blockIdx.x * 256 + threadIdx.x;
    if (n < N_NODES) {
        unsigned o = atomicAdd(counter, deg[n]);
        off[n] = o;
        cursor[n] = o;
    }
}

__global__ void k_scatter(const int* __restrict__ esrc, const int* __restrict__ edst,
                          const int* __restrict__ etype, const float* __restrict__ el,
                          const float* __restrict__ er, const float* __restrict__ ee,
                          unsigned* __restrict__ cursor, unsigned* __restrict__ ssrc,
                          unsigned* __restrict__ seid, float* __restrict__ slogit) {
    int e = blockIdx.x * 256 + threadIdx.x;
    if (e >= E_EDGES) return;
    int s = esrc[e], d = edst[e], t = etype[e];
    unsigned pos = atomicAdd(&cursor[d], 1u);
    ssrc[pos] = (unsigned)s;
    seid[pos] = (unsigned)e;
    float4 l = *reinterpret_cast<const float4*>(&el[s * 4]);
    float4 r = *reinterpret_cast<const float4*>(&er[d * 4]);
    float4 q = *reinterpret_cast<const float4*>(&ee[t * 4]);
    float4 z;
    z.x = l.x + r.x + q.x;
    z.y = l.y + r.y + q.y;
    z.z = l.z + r.z + q.z;
    z.w = l.w + r.w + q.w;
    z.x = z.x > 0.f ? z.x : NEG_SLOPE * z.x;
    z.y = z.y > 0.f ? z.y : NEG_SLOPE * z.y;
    z.z = z.z > 0.f ? z.z : NEG_SLOPE * z.z;
    z.w = z.w > 0.f ? z.w : NEG_SLOPE * z.w;
    *reinterpret_cast<float4*>(&slogit[(size_t)pos * 4]) = z;
}

// ---------------- per-dst softmax + aggregation ----------------
// one wave per node; two edges in flight (half-waves), bf16 feat, 16B/lane loads
__global__ __launch_bounds__(256) void k_agg(const unsigned* __restrict__ off, const unsigned* __restrict__ deg,
                                             const unsigned* __restrict__ ssrc, const unsigned* __restrict__ seid,
                                             const float* __restrict__ slogit, const short* __restrict__ featb,
                                             float* __restrict__ out, float* __restrict__ a_out) {
    const int wave = threadIdx.x >> 6;
    const int lane = threadIdx.x & 63;
    const int n = blockIdx.x * 4 + wave;
    if (n >= N_NODES) return;
    const int half = lane >> 5;        // which edge parity this lane works
    const int l32 = lane & 31;         // owns bf16 dims [l32*8, l32*8+8)
    const int h = l32 >> 3;            // head owning those dims
    const unsigned start = off[n];
    const unsigned cnt = deg[n];

    // pass A: global max per head (half-waves scan alternate edges, then merge)
    float m = -1e30f;
    for (unsigned i = half; i < cnt; i += 2)
        m = fmaxf(m, slogit[(size_t)(start + i) * 4 + h]);
    m = fmaxf(m, __shfl_xor(m, 32, 64));

    // pass B: sum + weighted aggregate (per-half, merged at end; same m so no rescale)
    float s = 0.f;
    float acc[8];
    #pragma unroll
    for (int j = 0; j < 8; ++j) acc[j] = 0.f;
    for (unsigned i = half; i < cnt; i += 2) {
        float lg = slogit[(size_t)(start + i) * 4 + h];
        float w = __expf(lg - m);
        s += w;
        unsigned src = ssrc[start + i];
        short8 f = *reinterpret_cast<const short8*>(&featb[(size_t)src * 256 + l32 * 8]);
        #pragma unroll
        for (int j = 0; j < 8; ++j) acc[j] += w * bf2f(f[j]);
    }
    s += __shfl_xor(s, 32, 64);
    #pragma unroll
    for (int j = 0; j < 8; ++j) acc[j] += __shfl_xor(acc[j], 32, 64);
    float inv = (cnt > 0) ? 1.f / s : 0.f;

    if (half == 0) {
        float4 o0, o1;
        o0.x = acc[0] * inv; o0.y = acc[1] * inv; o0.z = acc[2] * inv; o0.w = acc[3] * inv;
        o1.x = acc[4] * inv; o1.y = acc[5] * inv; o1.z = acc[6] * inv; o1.w = acc[7] * inv;
        *reinterpret_cast<float4*>(&out[(size_t)n * 256 + l32 * 8]) = o0;
        *reinterpret_cast<float4*>(&out[(size_t)n * 256 + l32 * 8 + 4]) = o1;
    }

    // pass C: normalized attention back to original edge order — all 64 lanes
    float m_h[4], inv_h[4];
    #pragma unroll
    for (int hh = 0; hh < 4; ++hh) {
        m_h[hh] = __shfl(m, hh * 8, 64);
        inv_h[hh] = __shfl(inv, hh * 8, 64);
    }
    const int hh = lane & 3;
    for (unsigned i = lane >> 2; i < cnt; i += 16) {
        float lg = slogit[(size_t)(start + i) * 4 + hh];
        a_out[(size_t)seid[start + i] * 4 + hh] = __expf(lg - m_h[hh]) * inv_h[hh];
    }
}

extern "C" void kernel_launch(void* const* d_in, const int* in_sizes, int n_in,
                              void* d_out, int out_size, void* d_ws, size_t ws_size,
                              hipStream_t stream) {
    const float* x        = (const float*)d_in[0];
    const int*   edge_src = (const int*)d_in[1];
    const int*   edge_dst = (const int*)d_in[2];
    const int*   edge_type= (const int*)d_in[3];
    const float* W        = (const float*)d_in[4];
    const float* edge_emb = (const float*)d_in[5];
    const float* W_e      = (const float*)d_in[6];
    const float* attn_l   = (const float*)d_in[7];
    const float* attn_r   = (const float*)d_in[8];
    const float* attn_e   = (const float*)d_in[9];

    float* out   = (float*)d_out;                              // N*H*D
    float* a_out = (float*)d_out + (size_t)N_NODES * 256;      // E*H

    // workspace layout (byte offsets) — featb now bf16 (25.6 MB), offsets kept stable
    char* ws = (char*)d_ws;
    short*    featb   = (short*)(ws + 0);                         // 25,600,000 B
    float*    el      = (float*)(ws + 51200000);                  // 800,000 B
    float*    er      = (float*)(ws + 52000000);                  // 800,000 B
    float*    ee      = (float*)(ws + 52800000);                  // 64 B
    unsigned* deg     = (unsigned*)(ws + 52800064);               // 200,000 B
    unsigned* off     = (unsigned*)(ws + 53000064);               // 200,000 B
    unsigned* cursor  = (unsigned*)(ws + 53200064);               // 200,000 B
    unsigned* counter = (unsigned*)(ws + 53400064);               // 64 B
    unsigned* ssrc    = (unsigned*)(ws + 53400128);               // 3,200,000 B
    unsigned* seid    = (unsigned*)(ws + 56600128);               // 3,200,000 B
    float*    slogit  = (float*)(ws + 59800128);                  // 12,800,000 B
    // Wt (bf16 256x256, 131072 B) aliases the seid region: dead before k_scatter writes seid
    short*    Wt      = (short*)(ws + 56600128);

    hipMemsetAsync(deg, 0, 200000, stream);
    hipMemsetAsync(counter, 0, 64, stream);

    k_wt<<<256, 256, 0, stream>>>(W, Wt);
    k_ee<<<T_TYPES, 256, 0, stream>>>(edge_emb, W_e, attn_e, ee);
    k_gemm<<<(N_NODES + 127) / 128, 512, 0, stream>>>(x, Wt, attn_l, attn_r, featb, el, er);
    k_hist<<<(E_EDGES + 255) / 256, 256, 0, stream>>>(edge_dst, deg);
    k_alloc<<<(N_NODES + 255) / 256, 256, 0, stream>>>(deg, off, cursor, counter);
    k_scatter<<<(E_EDGES + 255) / 256, 256, 0, stream>>>(edge_src, edge_dst, edge_type,
                                                         el, er, ee, cursor, ssrc, seid, slogit);
    k_agg<<<(N_NODES + 3) / 4, 256, 0, stream>>>(off, deg, ssrc, seid, slogit, featb, out, a_out);
}

// Round 4
// 217.842 us; speedup vs baseline: 7.4216x; 1.0511x over previous
//
#include <hip/hip_runtime.h>
#include <hip/hip_bf16.h>
#include <math.h>

#define N_NODES 50000
#define E_EDGES 800000
#define T_TYPES 3
#define NEG_SLOPE 0.2f

typedef __attribute__((ext_vector_type(8))) short short8;
typedef __attribute__((ext_vector_type(4))) float f32x4;

__device__ inline short f2bf(float f) {
    __hip_bfloat16 h = __float2bfloat16(f);
    union { __hip_bfloat16 b; short s; } u;
    u.b = h;
    return u.s;
}
__device__ inline float bf2f(short s) {
    union { unsigned u; float f; } v;
    v.u = ((unsigned)(unsigned short)s) << 16;
    return v.f;
}

// ---------------- prep: Wt[n][k] = bf16(W[k][n])  +  ee[t][h] ----------------
__global__ void k_prep(const float* __restrict__ W, short* __restrict__ Wt,
                       const float* __restrict__ edge_emb, const float* __restrict__ W_e,
                       const float* __restrict__ attn_e, float* __restrict__ ee) {
    if (blockIdx.x < 256) {
        int n = blockIdx.x;
        int k = threadIdx.x;
        Wt[n * 256 + k] = f2bf(W[k * 256 + n]);
    } else {
        int t = blockIdx.x - 256;
        int j = threadIdx.x;            // h*64 + fe
        int h = j >> 6;
        float ae = attn_e[j];
        float v = 0.f;
        #pragma unroll
        for (int k = 0; k < 64; ++k) v += edge_emb[t * 64 + k] * W_e[k * 256 + j];
        v *= ae;
        #pragma unroll
        for (int o = 32; o; o >>= 1) v += __shfl_xor(v, o, 64);
        if ((j & 63) == 0) ee[t * 4 + h] = v;
    }
}

// ---------------- feat(bf16) = x @ W via bf16 MFMA, fused el/er ----------------
// block = 256 threads (4 waves, one head-column each), tile 64 x 256, BK = 32
__global__ __launch_bounds__(256) void k_gemm(const float* __restrict__ x, const short* __restrict__ Wt,
                                              const float* __restrict__ attn_l, const float* __restrict__ attn_r,
                                              short* __restrict__ featb, float* __restrict__ el,
                                              float* __restrict__ er) {
    __shared__ short a_lds[64 * 40];    // [m][k] rows padded to 40 shorts
    const int tid = threadIdx.x;
    const int wc = tid >> 6;            // wave = head column
    const int lane = tid & 63;
    const int l15 = lane & 15;
    const int lq = lane >> 4;           // 0..3
    const int m0 = blockIdx.x * 64;

    f32x4 acc[4][4];
    #pragma unroll
    for (int mf = 0; mf < 4; ++mf)
        #pragma unroll
        for (int nf = 0; nf < 4; ++nf)
            acc[mf][nf] = (f32x4){0.f, 0.f, 0.f, 0.f};

    const int sr = tid >> 2;            // 0..63
    const int sc = (tid & 3) * 8;
    int gm = m0 + sr;
    if (gm >= N_NODES) gm = N_NODES - 1;
    const float* xrow = &x[(size_t)gm * 256];

    // prologue: load first K-slice into regs
    float4 v0 = *reinterpret_cast<const float4*>(&xrow[sc]);
    float4 v1 = *reinterpret_cast<const float4*>(&xrow[sc + 4]);

    #pragma unroll
    for (int k0 = 0; k0 < 256; k0 += 32) {
        short8 s;
        s[0] = f2bf(v0.x); s[1] = f2bf(v0.y); s[2] = f2bf(v0.z); s[3] = f2bf(v0.w);
        s[4] = f2bf(v1.x); s[5] = f2bf(v1.y); s[6] = f2bf(v1.z); s[7] = f2bf(v1.w);
        *reinterpret_cast<short8*>(&a_lds[sr * 40 + sc]) = s;
        if (k0 + 32 < 256) {            // prefetch next K-slice (latency hidden under MFMA phase)
            v0 = *reinterpret_cast<const float4*>(&xrow[k0 + 32 + sc]);
            v1 = *reinterpret_cast<const float4*>(&xrow[k0 + 32 + sc + 4]);
        }
        __syncthreads();

        short8 av[4], bv[4];
        #pragma unroll
        for (int mf = 0; mf < 4; ++mf)
            av[mf] = *reinterpret_cast<const short8*>(&a_lds[(mf * 16 + l15) * 40 + lq * 8]);
        #pragma unroll
        for (int nf = 0; nf < 4; ++nf) {
            int n = wc * 64 + nf * 16 + l15;
            bv[nf] = *reinterpret_cast<const short8*>(&Wt[(size_t)n * 256 + k0 + lq * 8]);
        }
        #pragma unroll
        for (int mf = 0; mf < 4; ++mf)
            #pragma unroll
            for (int nf = 0; nf < 4; ++nf)
                acc[mf][nf] = __builtin_amdgcn_mfma_f32_16x16x32_bf16(av[mf], bv[nf], acc[mf][nf], 0, 0, 0);
        __syncthreads();
    }

    // epilogue: write bf16 feat + fused el/er (f32 accuracy for logits)
    float al[4], ar[4];
    #pragma unroll
    for (int nf = 0; nf < 4; ++nf) {
        al[nf] = attn_l[wc * 64 + nf * 16 + l15];
        ar[nf] = attn_r[wc * 64 + nf * 16 + l15];
    }
    #pragma unroll
    for (int mf = 0; mf < 4; ++mf) {
        #pragma unroll
        for (int i = 0; i < 4; ++i) {
            int m = m0 + mf * 16 + lq * 4 + i;
            bool ok = m < N_NODES;
            float pl = 0.f, pr = 0.f;
            #pragma unroll
            for (int nf = 0; nf < 4; ++nf) {
                float v = acc[mf][nf][i];
                if (ok) featb[(size_t)m * 256 + wc * 64 + nf * 16 + l15] = f2bf(v);
                pl += v * al[nf];
                pr += v * ar[nf];
            }
            #pragma unroll
            for (int o = 1; o < 16; o <<= 1) {
                pl += __shfl_xor(pl, o, 64);
                pr += __shfl_xor(pr, o, 64);
            }
            if (ok && l15 == 0) {
                el[m * 4 + wc] = pl;
                er[m * 4 + wc] = pr;
            }
        }
    }
}

// ---------------- CSR build ----------------
__global__ void k_hist(const int* __restrict__ edst, unsigned* __restrict__ deg) {
    int e = blockIdx.x * 256 + threadIdx.x;
    if (e < E_EDGES) atomicAdd(&deg[edst[e]], 1u);
}

__global__ void k_alloc(const unsigned* __restrict__ deg, unsigned* __restrict__ off,
                        unsigned* __restrict__ cursor, unsigned* __restrict__ counter) {
    int n = blockIdx.x * 256 + threadIdx.x;
    if (n < N_NODES) {
        unsigned o = atomicAdd(counter, deg[n]);
        off[n] = o;
        cursor[n] = o;
    }
}

__global__ void k_scatter(const int* __restrict__ esrc, const int* __restrict__ edst,
                          const int* __restrict__ etype, const float* __restrict__ el,
                          const float* __restrict__ er, const float* __restrict__ ee,
                          unsigned* __restrict__ cursor, unsigned* __restrict__ ssrc,
                          unsigned* __restrict__ seid, float* __restrict__ slogit) {
    int e = blockIdx.x * 256 + threadIdx.x;
    if (e >= E_EDGES) return;
    int s = esrc[e], d = edst[e], t = etype[e];
    unsigned pos = atomicAdd(&cursor[d], 1u);
    ssrc[pos] = (unsigned)s;
    seid[pos] = (unsigned)e;
    float4 l = *reinterpret_cast<const float4*>(&el[s * 4]);
    float4 r = *reinterpret_cast<const float4*>(&er[d * 4]);
    float4 q = *reinterpret_cast<const float4*>(&ee[t * 4]);
    float4 z;
    z.x = l.x + r.x + q.x;
    z.y = l.y + r.y + q.y;
    z.z = l.z + r.z + q.z;
    z.w = l.w + r.w + q.w;
    z.x = z.x > 0.f ? z.x : NEG_SLOPE * z.x;
    z.y = z.y > 0.f ? z.y : NEG_SLOPE * z.y;
    z.z = z.z > 0.f ? z.z : NEG_SLOPE * z.z;
    z.w = z.w > 0.f ? z.w : NEG_SLOPE * z.w;
    *reinterpret_cast<float4*>(&slogit[(size_t)pos * 4]) = z;
}

// ---------------- per-dst softmax + aggregation ----------------
// one wave per node; half-waves own alternate edges; 2x unroll -> 4 gathers in flight
__global__ __launch_bounds__(256) void k_agg(const unsigned* __restrict__ off, const unsigned* __restrict__ deg,
                                             const unsigned* __restrict__ ssrc, const unsigned* __restrict__ seid,
                                             const float* __restrict__ slogit, const short* __restrict__ featb,
                                             float* __restrict__ out, float* __restrict__ a_out) {
    const int wave = threadIdx.x >> 6;
    const int lane = threadIdx.x & 63;
    const int n = blockIdx.x * 4 + wave;
    if (n >= N_NODES) return;
    const int half = lane >> 5;        // edge parity this lane works
    const int l32 = lane & 31;         // owns bf16 dims [l32*8, l32*8+8)
    const int h = l32 >> 3;            // head owning those dims
    const unsigned start = off[n];
    const unsigned cnt = deg[n];

    // pass A: global max per head (2x unrolled)
    float m = -1e30f;
    {
        unsigned i = half;
        for (; i + 2 < cnt; i += 4) {
            float a = slogit[(size_t)(start + i) * 4 + h];
            float b = slogit[(size_t)(start + i + 2) * 4 + h];
            m = fmaxf(m, fmaxf(a, b));
        }
        for (; i < cnt; i += 2)
            m = fmaxf(m, slogit[(size_t)(start + i) * 4 + h]);
    }
    m = fmaxf(m, __shfl_xor(m, 32, 64));

    // pass B: sum + weighted aggregate (2x unrolled, independent chains)
    float s0 = 0.f, s1 = 0.f;
    float a0[8], a1[8];
    #pragma unroll
    for (int j = 0; j < 8; ++j) { a0[j] = 0.f; a1[j] = 0.f; }
    {
        unsigned i = half;
        for (; i + 2 < cnt; i += 4) {
            unsigned src0 = ssrc[start + i];
            unsigned src1 = ssrc[start + i + 2];
            float lg0 = slogit[(size_t)(start + i) * 4 + h];
            float lg1 = slogit[(size_t)(start + i + 2) * 4 + h];
            short8 f0 = *reinterpret_cast<const short8*>(&featb[(size_t)src0 * 256 + l32 * 8]);
            short8 f1 = *reinterpret_cast<const short8*>(&featb[(size_t)src1 * 256 + l32 * 8]);
            float w0 = __expf(lg0 - m);
            float w1 = __expf(lg1 - m);
            s0 += w0; s1 += w1;
            #pragma unroll
            for (int j = 0; j < 8; ++j) {
                a0[j] += w0 * bf2f(f0[j]);
                a1[j] += w1 * bf2f(f1[j]);
            }
        }
        for (; i < cnt; i += 2) {
            unsigned src0 = ssrc[start + i];
            float lg0 = slogit[(size_t)(start + i) * 4 + h];
            short8 f0 = *reinterpret_cast<const short8*>(&featb[(size_t)src0 * 256 + l32 * 8]);
            float w0 = __expf(lg0 - m);
            s0 += w0;
            #pragma unroll
            for (int j = 0; j < 8; ++j) a0[j] += w0 * bf2f(f0[j]);
        }
    }
    float s = s0 + s1;
    s += __shfl_xor(s, 32, 64);
    #pragma unroll
    for (int j = 0; j < 8; ++j) {
        a0[j] += a1[j];
        a0[j] += __shfl_xor(a0[j], 32, 64);
    }
    float inv = (cnt > 0) ? 1.f / s : 0.f;

    if (half == 0) {
        float4 o0, o1;
        o0.x = a0[0] * inv; o0.y = a0[1] * inv; o0.z = a0[2] * inv; o0.w = a0[3] * inv;
        o1.x = a0[4] * inv; o1.y = a0[5] * inv; o1.z = a0[6] * inv; o1.w = a0[7] * inv;
        *reinterpret_cast<float4*>(&out[(size_t)n * 256 + l32 * 8]) = o0;
        *reinterpret_cast<float4*>(&out[(size_t)n * 256 + l32 * 8 + 4]) = o1;
    }

    // pass C: normalized attention back to original edge order — all 64 lanes
    float m_h[4], inv_h[4];
    #pragma unroll
    for (int hh = 0; hh < 4; ++hh) {
        m_h[hh] = __shfl(m, hh * 8, 64);
        inv_h[hh] = __shfl(inv, hh * 8, 64);
    }
    const int hh = lane & 3;
    for (unsigned i = lane >> 2; i < cnt; i += 16) {
        float lg = slogit[(size_t)(start + i) * 4 + hh];
        a_out[(size_t)seid[start + i] * 4 + hh] = __expf(lg - m_h[hh]) * inv_h[hh];
    }
}

extern "C" void kernel_launch(void* const* d_in, const int* in_sizes, int n_in,
                              void* d_out, int out_size, void* d_ws, size_t ws_size,
                              hipStream_t stream) {
    const float* x        = (const float*)d_in[0];
    const int*   edge_src = (const int*)d_in[1];
    const int*   edge_dst = (const int*)d_in[2];
    const int*   edge_type= (const int*)d_in[3];
    const float* W        = (const float*)d_in[4];
    const float* edge_emb = (const float*)d_in[5];
    const float* W_e      = (const float*)d_in[6];
    const float* attn_l   = (const float*)d_in[7];
    const float* attn_r   = (const float*)d_in[8];
    const float* attn_e   = (const float*)d_in[9];

    float* out   = (float*)d_out;                              // N*H*D
    float* a_out = (float*)d_out + (size_t)N_NODES * 256;      // E*H

    // workspace layout (byte offsets)
    char* ws = (char*)d_ws;
    short*    featb   = (short*)(ws + 0);                         // 25,600,000 B
    float*    el      = (float*)(ws + 25600000);                  // 800,000 B
    float*    er      = (float*)(ws + 26400000);                  // 800,000 B
    float*    ee      = (float*)(ws + 27200000);                  // 64 B
    unsigned* deg     = (unsigned*)(ws + 27200064);               // 200,000 B
    unsigned* counter = (unsigned*)(ws + 27400064);               // 64 B   (memset with deg)
    unsigned* off     = (unsigned*)(ws + 27400128);               // 200,000 B
    unsigned* cursor  = (unsigned*)(ws + 27600128);               // 200,000 B
    unsigned* ssrc    = (unsigned*)(ws + 27800128);               // 3,200,000 B
    unsigned* seid    = (unsigned*)(ws + 31000128);               // 3,200,000 B
    float*    slogit  = (float*)(ws + 34200128);                  // 12,800,000 B
    short*    Wt      = (short*)(ws + 47000128);                  // 131,072 B

    hipMemsetAsync(deg, 0, 200064, stream);   // covers deg + counter

    k_prep<<<256 + T_TYPES, 256, 0, stream>>>(W, Wt, edge_emb, W_e, attn_e, ee);
    k_gemm<<<(N_NODES + 63) / 64, 256, 0, stream>>>(x, Wt, attn_l, attn_r, featb, el, er);
    k_hist<<<(E_EDGES + 255) / 256, 256, 0, stream>>>(edge_dst, deg);
    k_alloc<<<(N_NODES + 255) / 256, 256, 0, stream>>>(deg, off, cursor, counter);
    k_scatter<<<(E_EDGES + 255) / 256, 256, 0, stream>>>(edge_src, edge_dst, edge_type,
                                                         el, er, ee, cursor, ssrc, seid, slogit);
    k_agg<<<(N_NODES + 3) / 4, 256, 0, stream>>>(off, deg, ssrc, seid, slogit, featb, out, a_out);
}